// Round 9
// baseline (168.629 us; speedup 1.0000x reference)
//
#include <hip/hip_runtime.h>
#include <cstdint>

#define T_DIM 1000
#define B_DIM 64
#define C_DIM 256
#define L_DIM 100
#define S_DIM (2 * L_DIM + 1) /* 201 */
#define CH 16                 /* steps per chunk */
#define MEAN_BLOCKS 2048      /* 64 b x 8 slices x 4 quarters */
#define MEAN_ROWS 125

// DPP cross-lane (VALU-rate). wave_shr:1=0x138, row_shr:n=0x110|n,
// row_bcast:15=0x142, row_bcast:31=0x143. bound_ctrl=true -> invalid lanes read 0.
#define DPP_I(x, ctrl) __builtin_amdgcn_update_dpp(0, (x), (ctrl), 0xF, 0xF, true)
#define DPP_F(x, ctrl) __int_as_float(DPP_I(__float_as_int(x), (ctrl)))

// Wave-wide max of non-negative values; exact, order-independent.
__device__ __forceinline__ float wave_max_dpp(float x) {
    x = fmaxf(x, DPP_F(x, 0x111)); // row_shr:1
    x = fmaxf(x, DPP_F(x, 0x112)); // row_shr:2
    x = fmaxf(x, DPP_F(x, 0x114)); // row_shr:4
    x = fmaxf(x, DPP_F(x, 0x118)); // row_shr:8
    x = fmaxf(x, DPP_F(x, 0x142)); // row_bcast:15
    x = fmaxf(x, DPP_F(x, 0x143)); // row_bcast:31 -> lane 63 has wave max
    return __int_as_float(__builtin_amdgcn_readlane(__float_as_int(x), 63));
}

// Async full-row global->LDS: 64 lanes x 16B = 1KB row in ONE instruction.
// Replaces 3 per-lane scattered gathers/step (~64 TA-cyc each -- the R3..R8
// bottleneck) with one coalesced fire-and-forget DMA (~4 cyc issue).
// LDS dest = wave-uniform base + lane*16 (m104/m108 semantics) == row layout.
__device__ __forceinline__ void row_to_lds(const float* g, float* lds_base) {
    __builtin_amdgcn_global_load_lds(
        (const __attribute__((address_space(1))) void*)g,
        (__attribute__((address_space(3))) void*)lds_base,
        16, 0, 0);
}

// Fused kernel, 64-thread blocks:
//   blocks [0,B): CTC alpha recursion, single wave. The wave issues async
//     row loads for chunk c+1 (16 x global_load_lds), computes chunk c from
//     LDS (per-lane c1/c3 selection moves to the LDS pipe), __syncthreads
//     drains vmcnt (m97-safe pattern; nothing for the compiler to remat-sink).
//   blocks [B, B+2048): mean-over-time exp(log_probs) -> atomicAdd ws_mean.
__global__ __launch_bounds__(64, 1) void ctc_fused(
        const float* __restrict__ lp,       // (T,B,C)
        const int* __restrict__ tgt,        // (B*L,)
        const int* __restrict__ il,         // (B,)
        const int* __restrict__ tl,         // (B,)
        float* __restrict__ ws_mean,        // (B,C) zero-initialized
        float* __restrict__ ws_loss) {      // (B,)
    const int blk = blockIdx.x;
    const uint32_t rstride = B_DIM * C_DIM;

    if (blk >= B_DIM) {
        // ---- mean_probs pass: (b, slice, quarter), 64 classes per block ----
        const int mb = blk - B_DIM;
        const int b = mb >> 5;
        const int sub = mb & 31;
        const int quarter = sub & 3;
        const int slice = sub >> 2;
        const int c = (quarter << 6) + threadIdx.x;
        const float* p = lp + (size_t)b * C_DIM + c + (size_t)(slice * MEAN_ROWS) * rstride;
        float s0 = 0.f, s1 = 0.f, s2 = 0.f, s3 = 0.f, s4 = 0.f;
        for (int t = 0; t < MEAN_ROWS; t += 5) {
            s0 += __expf(p[(size_t)(t + 0) * rstride]);
            s1 += __expf(p[(size_t)(t + 1) * rstride]);
            s2 += __expf(p[(size_t)(t + 2) * rstride]);
            s3 += __expf(p[(size_t)(t + 3) * rstride]);
            s4 += __expf(p[(size_t)(t + 4) * rstride]);
        }
        atomicAdd(&ws_mean[b * C_DIM + c], (s0 + s1 + s2 + s3 + s4) * (1.0f / T_DIM));
        return;
    }

    // ---- CTC pass: one 64-lane wave per batch sample ----
    __shared__ float rows[2][CH][C_DIM]; // ping-pong row buffer, 32 KB

    const int lane = threadIdx.x;
    const int b = blk;
    const int* trow = tgt + b * L_DIM;
    const int ilen = il[b];
    const int tlen = tl[b];

    const int i1 = 2 * lane;
    const int i3 = 2 * lane + 1;
    const int c1 = (i1 < L_DIM) ? trow[i1] : 0;
    const int c3 = (i3 < L_DIM) ? trow[i3] : 0;
    const int c1m = (i1 >= 1 && i1 - 1 < L_DIM) ? trow[i1 - 1] : -1;
    const float m1 = ((i1 >= 1) && (c1 != c1m)) ? 1.0f : 0.0f;
    const float m3 = (c3 != c1) ? 1.0f : 0.0f;

    // invalid states (s >= S) must be zeroed at each renorm (R2 lesson)
    const float f0 = (4 * lane + 0 < S_DIM) ? 1.0f : 0.0f;
    const float f1 = (4 * lane + 1 < S_DIM) ? 1.0f : 0.0f;
    const float f2 = (4 * lane + 2 < S_DIM) ? 1.0f : 0.0f;
    const float f3 = (4 * lane + 3 < S_DIM) ? 1.0f : 0.0f;

    const float* base = lp + (size_t)b * C_DIM;

    // t=0 init (bit-identical to R5/R6/R8)
    float a0 = 0.f, a1 = 0.f, a2 = 0.f, a3 = 0.f;
    {
        float i0 = __expf(base[0]);
        float i1v = __expf(base[c1]);
        if (lane == 0) { a0 = i0; a1 = i1v; }
    }
    float ls = 0.f;

    // one recursion step -- bit-identical to R5/R6/R8 (absmax must stay 96.0)
    auto step = [&](float lb, float l1, float l3) {
        const float pb  = __expf(lb);
        const float p1e = __expf(l1);
        const float p3e = __expf(l3);
        const float p3 = DPP_F(a3, 0x138); // prev lane's a3; lane0 -> 0
        const float a01 = a0 + a1;
        const float n0 = (a0 + p3) * pb;
        const float n1 = fmaf(m1, p3, a01) * p1e;
        const float n2 = (a2 + a1) * pb;
        const float n3 = (fmaf(m3, a1, a2) + a3) * p3e;
        a0 = n0; a1 = n1; a2 = n2; a3 = n3;
    };

#define RENORM() do {                                                       \
        a0 *= f0; a1 *= f1; a2 *= f2; a3 *= f3;                             \
        const float mx = wave_max_dpp(fmaxf(fmaxf(a0, a1), fmaxf(a2, a3))); \
        const float inv = __builtin_amdgcn_rcpf(mx);                        \
        ls -= __logf(inv);                                                  \
        a0 *= inv; a1 *= inv; a2 *= inv; a3 *= inv;                         \
    } while (0)

    // issue chunk cc's 16 async row loads (coalesced, no VGPR round-trip)
    auto produce = [&](int cc) {
        const int p = cc & 1;
        const int tstart = 1 + cc * CH;
#pragma unroll
        for (int d = 0; d < CH; ++d) {
            int t = tstart + d; t = (t < ilen) ? t : (ilen - 1);
            const float* g = base + (size_t)t * rstride + (lane << 2);
            row_to_lds(g, &rows[p][d][0]);
        }
    };

    // consume one chunk from LDS; renorm at d&7==7 (t = 8+16cc, 16+16cc --
    // exactly t%8==0, same renorm set as R5/R6/R8)
    auto consume = [&](int cc) {
        const int p = cc & 1;
        const int tstart = 1 + cc * CH;
        if (tstart + CH <= ilen) {
#pragma unroll
            for (int d = 0; d < CH; ++d) {
                step(rows[p][d][0], rows[p][d][c1], rows[p][d][c3]);
                if ((d & 7) == 7) RENORM();
            }
        } else {
#pragma unroll
            for (int d = 0; d < CH; ++d) {
                if (tstart + d < ilen) {
                    step(rows[p][d][0], rows[p][d][c1], rows[p][d][c3]);
                    if ((d & 7) == 7) RENORM();
                }
            }
        }
    };

    const int nchunks = (ilen - 1 + CH - 1) / CH;
    produce(0);
    __syncthreads(); // s_waitcnt vmcnt(0) + barrier: chunk 0 resident
    for (int c = 0; c < nchunks; ++c) {
        produce(c + 1); // async into other buffer (last iter: clamped junk, never read)
        consume(c);     // LDS reads + serial chain, overlaps the loads above
        __syncthreads(); // drain vmcnt: chunk c+1 resident
    }
#undef RENORM

    // final: ll = log(alpha[2tl] + alpha[2tl-1]) + ls
    const int s_hi = 2 * tlen;
    const int s_lo = 2 * tlen - 1;
    const int slot_hi = s_hi & 3, lane_hi = min(s_hi >> 2, 63);
    const int slot_lo = s_lo & 3, lane_lo = min(s_lo >> 2, 63);
    float ch = (slot_hi == 0) ? a0 : (slot_hi == 1) ? a1 : (slot_hi == 2) ? a2 : a3;
    float cl = (slot_lo == 0) ? a0 : (slot_lo == 1) ? a1 : (slot_lo == 2) ? a2 : a3;
    const float vh = __shfl(ch, lane_hi, 64);
    const float vl = __shfl(cl, lane_lo, 64);
    if (lane == 0) {
        const float s = vh + vl;
        const float loss = (s > 0.f) ? -(__logf(s) + ls) : 0.0f; // zero_infinity
        ws_loss[b] = loss;
    }
}

// out = (sum_j focal_j / (B*L)) * (sum_b loss_b / B)
__global__ __launch_bounds__(256) void ctc_finalize(
        const float* __restrict__ ws_mean, const float* __restrict__ ws_loss,
        const int* __restrict__ tgt, float* __restrict__ out) {
    const int tid = threadIdx.x;
    float fsum = 0.f;
#pragma unroll
    for (int k = 0; k < (B_DIM * L_DIM) / 256; ++k) {
        const int j = tid + k * 256;
        const int b = j / L_DIM;
        const int c = tgt[j];
        const float p = ws_mean[b * C_DIM + c];
        const float w = 1.0f - p;
        fsum += w * w;
    }
    float lsum = (tid < B_DIM) ? ws_loss[tid] : 0.f;
#pragma unroll
    for (int off = 32; off > 0; off >>= 1) {
        fsum += __shfl_down(fsum, off, 64);
        lsum += __shfl_down(lsum, off, 64);
    }
    __shared__ float sf[4], sl[4];
    const int w = tid >> 6;
    if ((tid & 63) == 0) { sf[w] = fsum; sl[w] = lsum; }
    __syncthreads();
    if (tid == 0) {
        const float F = sf[0] + sf[1] + sf[2] + sf[3];
        const float Lo = sl[0] + sl[1] + sl[2] + sl[3];
        out[0] = (F / (float)(B_DIM * L_DIM)) * (Lo / (float)B_DIM);
    }
}

extern "C" void kernel_launch(void* const* d_in, const int* in_sizes, int n_in,
                              void* d_out, int out_size, void* d_ws, size_t ws_size,
                              hipStream_t stream) {
    const float* lp = (const float*)d_in[0];
    const int* tgt = (const int*)d_in[1];
    const int* il = (const int*)d_in[2];
    const int* tl = (const int*)d_in[3];
    float* ws_mean = (float*)d_ws;               // B*C floats (atomicAdd target)
    float* ws_loss = ws_mean + B_DIM * C_DIM;    // B floats

    hipMemsetAsync(ws_mean, 0, B_DIM * C_DIM * sizeof(float), stream);
    ctc_fused<<<dim3(B_DIM + MEAN_BLOCKS), dim3(64), 0, stream>>>(
        lp, tgt, il, tl, ws_mean, ws_loss);
    ctc_finalize<<<dim3(1), dim3(256), 0, stream>>>(ws_mean, ws_loss, tgt, (float*)d_out);
}

// Round 10
// 137.363 us; speedup vs baseline: 1.2276x; 1.2276x over previous
//
#include <hip/hip_runtime.h>
#include <cstdint>

#define T_DIM 1000
#define B_DIM 64
#define C_DIM 256
#define L_DIM 100
#define S_DIM (2 * L_DIM + 1) /* 201 */
#define CH 32                 /* steps per chunk */
#define NPROD 7               /* producer waves (block = 8 waves) */
#define RPW 5                 /* ceil(CH/NPROD) rows per producer wave */
#define MEAN_BLOCKS 256       /* 64 b x 4 ; each block covers 2 of 8 T-slices */
#define MEAN_ROWS 125

// DPP cross-lane (VALU-rate). wave_shr:1=0x138, row_shr:n=0x110|n,
// row_bcast:15=0x142, row_bcast:31=0x143. bound_ctrl=true -> invalid lanes read 0.
#define DPP_I(x, ctrl) __builtin_amdgcn_update_dpp(0, (x), (ctrl), 0xF, 0xF, true)
#define DPP_F(x, ctrl) __int_as_float(DPP_I(__float_as_int(x), (ctrl)))

// Empty inline-asm pin: emits NO instruction, but forces the value to be
// materialized here (stops the remat-sink that erased R3/R5/R6's prefetch).
#define PIN(x) asm volatile("" : "+v"(x))

// Wave-wide max of non-negative values; exact, order-independent.
__device__ __forceinline__ float wave_max_dpp(float x) {
    x = fmaxf(x, DPP_F(x, 0x111)); // row_shr:1
    x = fmaxf(x, DPP_F(x, 0x112)); // row_shr:2
    x = fmaxf(x, DPP_F(x, 0x114)); // row_shr:4
    x = fmaxf(x, DPP_F(x, 0x118)); // row_shr:8
    x = fmaxf(x, DPP_F(x, 0x142)); // row_bcast:15
    x = fmaxf(x, DPP_F(x, 0x143)); // row_bcast:31 -> lane 63 has wave max
    return __int_as_float(__builtin_amdgcn_readlane(__float_as_int(x), 63));
}

// Fused kernel, 512-thread blocks:
//   blocks [0,B): CTC alpha recursion.
//     wave 0  = consumer: serial chain, reads PRE-EXP'D values from LDS only
//               (3 ds_read + ~12 VALU per step; zero transcendentals on chain).
//     waves 1-7 = producers: per chunk, each loads 5 full rows COALESCED
//               (one global_load_dwordx4 per row -> no TA scatter, unlike R8),
//               pins them (no remat-sink, unlike R3/R5/R6), applies __expf to
//               the whole row, stores to ping-pong LDS. Outstanding bytes scale
//               with wave count (~35 KB/block), dodging R9's LDS-DMA queue cap.
//   blocks [B, B+256): mean-over-time exp(log_probs) -> atomicAdd ws_mean.
__global__ __launch_bounds__(512, 1) void ctc_fused(
        const float* __restrict__ lp,       // (T,B,C)
        const int* __restrict__ tgt,        // (B*L,)
        const int* __restrict__ il,         // (B,)
        const int* __restrict__ tl,         // (B,)
        float* __restrict__ ws_mean,        // (B,C) zero-initialized
        float* __restrict__ ws_loss) {      // (B,)
    const int blk = blockIdx.x;
    const uint32_t rstride = B_DIM * C_DIM;

    if (blk >= B_DIM) {
        // ---- mean_probs pass: block = (b, slicepair); thread = (half, c) ----
        const int mb = blk - B_DIM;
        const int b = mb >> 2;
        const int half = threadIdx.x >> 8;         // 0/1
        const int c = threadIdx.x & 255;
        const int slice = ((mb & 3) << 1) + half;  // 0..7, 125 rows each
        const float* p = lp + (size_t)b * C_DIM + c + (size_t)(slice * MEAN_ROWS) * rstride;
        float s0 = 0.f, s1 = 0.f, s2 = 0.f, s3 = 0.f, s4 = 0.f;
        for (int t = 0; t < MEAN_ROWS; t += 5) {
            s0 += __expf(p[(size_t)(t + 0) * rstride]);
            s1 += __expf(p[(size_t)(t + 1) * rstride]);
            s2 += __expf(p[(size_t)(t + 2) * rstride]);
            s3 += __expf(p[(size_t)(t + 3) * rstride]);
            s4 += __expf(p[(size_t)(t + 4) * rstride]);
        }
        atomicAdd(&ws_mean[b * C_DIM + c], (s0 + s1 + s2 + s3 + s4) * (1.0f / T_DIM));
        return;
    }

    // ---- CTC pass ----
    __shared__ __align__(16) float rows[2][CH][C_DIM]; // exp'd rows, 64 KB

    const int tid = threadIdx.x;
    const int lane = tid & 63;
    const int wave = tid >> 6;
    const int b = blk;
    const int* trow = tgt + b * L_DIM;
    const int ilen = il[b];
    const int tlen = tl[b];

    const int i1 = 2 * lane;
    const int i3 = 2 * lane + 1;
    const int c1 = (i1 < L_DIM) ? trow[i1] : 0;
    const int c3 = (i3 < L_DIM) ? trow[i3] : 0;
    const int c1m = (i1 >= 1 && i1 - 1 < L_DIM) ? trow[i1 - 1] : -1;
    const float m1 = ((i1 >= 1) && (c1 != c1m)) ? 1.0f : 0.0f;
    const float m3 = (c3 != c1) ? 1.0f : 0.0f;

    // invalid states (s >= S) must be zeroed at each renorm (R2 lesson)
    const float f0 = (4 * lane + 0 < S_DIM) ? 1.0f : 0.0f;
    const float f1 = (4 * lane + 1 < S_DIM) ? 1.0f : 0.0f;
    const float f2 = (4 * lane + 2 < S_DIM) ? 1.0f : 0.0f;
    const float f3 = (4 * lane + 3 < S_DIM) ? 1.0f : 0.0f;

    const float* base = lp + (size_t)b * C_DIM;

    // t=0 init (bit-identical to R5..R9)
    float a0 = 0.f, a1 = 0.f, a2 = 0.f, a3 = 0.f;
    {
        float i0 = __expf(base[0]);
        float i1v = __expf(base[c1]);
        if (lane == 0 && wave == 0) { a0 = i0; a1 = i1v; }
    }
    float ls = 0.f;

    // producer: 5 coalesced row loads (phase 1), pin, exp + LDS store (phase 2)
    auto produce = [&](int cc) {
        const int p = cc & 1;
        const int tstart = 1 + cc * CH;
        float4 v[RPW];
#pragma unroll
        for (int k = 0; k < RPW; ++k) {
            const int d = (wave - 1) + NPROD * k;
            if (d < CH) {
                int t = tstart + d; t = (t < ilen) ? t : (ilen - 1);
                v[k] = *(const float4*)(base + (size_t)t * rstride + (lane << 2));
            }
        }
#pragma unroll
        for (int k = 0; k < RPW; ++k) {
            const int d = (wave - 1) + NPROD * k;
            if (d < CH) { PIN(v[k].x); PIN(v[k].y); PIN(v[k].z); PIN(v[k].w); }
        }
#pragma unroll
        for (int k = 0; k < RPW; ++k) {
            const int d = (wave - 1) + NPROD * k;
            if (d < CH) {
                float4 e;
                e.x = __expf(v[k].x); e.y = __expf(v[k].y);
                e.z = __expf(v[k].z); e.w = __expf(v[k].w);
                *(float4*)&rows[p][d][lane << 2] = e;
            }
        }
    };

    // consumer step: inputs are already exp'd (bitwise-identical to computing
    // __expf locally -- same v_exp_f32 on same inputs). absmax must stay 96.0.
    auto step = [&](float pb, float p1e, float p3e) {
        const float p3 = DPP_F(a3, 0x138); // prev lane's a3; lane0 -> 0
        const float a01 = a0 + a1;
        const float n0 = (a0 + p3) * pb;
        const float n1 = fmaf(m1, p3, a01) * p1e;
        const float n2 = (a2 + a1) * pb;
        const float n3 = (fmaf(m3, a1, a2) + a3) * p3e;
        a0 = n0; a1 = n1; a2 = n2; a3 = n3;
    };

#define RENORM() do {                                                       \
        a0 *= f0; a1 *= f1; a2 *= f2; a3 *= f3;                             \
        const float mx = wave_max_dpp(fmaxf(fmaxf(a0, a1), fmaxf(a2, a3))); \
        const float inv = __builtin_amdgcn_rcpf(mx);                        \
        ls -= __logf(inv);                                                  \
        a0 *= inv; a1 *= inv; a2 *= inv; a3 *= inv;                         \
    } while (0)

    // consume chunk cc; renorms at d&7==7 -> t = 8,16,24,32 (mod 32) == all
    // t%8==0 in range: EXACTLY R5/R9's renorm set (last at t=992 for T=1000).
    auto consume = [&](int cc) {
        const int p = cc & 1;
        const int tstart = 1 + cc * CH;
        if (tstart + CH <= ilen) {
#pragma unroll
            for (int d = 0; d < CH; ++d) {
                step(rows[p][d][0], rows[p][d][c1], rows[p][d][c3]);
                if ((d & 7) == 7) RENORM();
            }
        } else {
#pragma unroll
            for (int d = 0; d < CH; ++d) {
                if (tstart + d < ilen) {
                    step(rows[p][d][0], rows[p][d][c1], rows[p][d][c3]);
                    if ((d & 7) == 7) RENORM();
                }
            }
        }
    };

    const int nchunks = (ilen - 1 + CH - 1) / CH;
    if (wave != 0) produce(0);
    __syncthreads();
    for (int c = 0; c < nchunks; ++c) {
        if (wave != 0) produce(c + 1); // other parity; last iter clamped junk, never read
        else consume(c);
        __syncthreads();
    }
#undef RENORM

    if (wave != 0) return;

    // final: ll = log(alpha[2tl] + alpha[2tl-1]) + ls   (consumer wave only)
    const int s_hi = 2 * tlen;
    const int s_lo = 2 * tlen - 1;
    const int slot_hi = s_hi & 3, lane_hi = min(s_hi >> 2, 63);
    const int slot_lo = s_lo & 3, lane_lo = min(s_lo >> 2, 63);
    float ch = (slot_hi == 0) ? a0 : (slot_hi == 1) ? a1 : (slot_hi == 2) ? a2 : a3;
    float cl = (slot_lo == 0) ? a0 : (slot_lo == 1) ? a1 : (slot_lo == 2) ? a2 : a3;
    const float vh = __shfl(ch, lane_hi, 64);
    const float vl = __shfl(cl, lane_lo, 64);
    if (lane == 0) {
        const float s = vh + vl;
        const float loss = (s > 0.f) ? -(__logf(s) + ls) : 0.0f; // zero_infinity
        ws_loss[b] = loss;
    }
}

// out = (sum_j focal_j / (B*L)) * (sum_b loss_b / B)
__global__ __launch_bounds__(256) void ctc_finalize(
        const float* __restrict__ ws_mean, const float* __restrict__ ws_loss,
        const int* __restrict__ tgt, float* __restrict__ out) {
    const int tid = threadIdx.x;
    float fsum = 0.f;
#pragma unroll
    for (int k = 0; k < (B_DIM * L_DIM) / 256; ++k) {
        const int j = tid + k * 256;
        const int b = j / L_DIM;
        const int c = tgt[j];
        const float p = ws_mean[b * C_DIM + c];
        const float w = 1.0f - p;
        fsum += w * w;
    }
    float lsum = (tid < B_DIM) ? ws_loss[tid] : 0.f;
#pragma unroll
    for (int off = 32; off > 0; off >>= 1) {
        fsum += __shfl_down(fsum, off, 64);
        lsum += __shfl_down(lsum, off, 64);
    }
    __shared__ float sf[4], sl[4];
    const int w = tid >> 6;
    if ((tid & 63) == 0) { sf[w] = fsum; sl[w] = lsum; }
    __syncthreads();
    if (tid == 0) {
        const float F = sf[0] + sf[1] + sf[2] + sf[3];
        const float Lo = sl[0] + sl[1] + sl[2] + sl[3];
        out[0] = (F / (float)(B_DIM * L_DIM)) * (Lo / (float)B_DIM);
    }
}

extern "C" void kernel_launch(void* const* d_in, const int* in_sizes, int n_in,
                              void* d_out, int out_size, void* d_ws, size_t ws_size,
                              hipStream_t stream) {
    const float* lp = (const float*)d_in[0];
    const int* tgt = (const int*)d_in[1];
    const int* il = (const int*)d_in[2];
    const int* tl = (const int*)d_in[3];
    float* ws_mean = (float*)d_ws;               // B*C floats (atomicAdd target)
    float* ws_loss = ws_mean + B_DIM * C_DIM;    // B floats

    hipMemsetAsync(ws_mean, 0, B_DIM * C_DIM * sizeof(float), stream);
    ctc_fused<<<dim3(B_DIM + MEAN_BLOCKS), dim3(512), 0, stream>>>(
        lp, tgt, il, tl, ws_mean, ws_loss);
    ctc_finalize<<<dim3(1), dim3(256), 0, stream>>>(ws_mean, ws_loss, tgt, (float*)d_out);
}